// Round 2
// baseline (208.926 us; speedup 1.0000x reference)
//
#include <hip/hip_runtime.h>

// ---------------- types / helpers ----------------
typedef __bf16 bf16x8 __attribute__((ext_vector_type(8)));
typedef float  f32x4  __attribute__((ext_vector_type(4)));

#define MFMA(a, b, c) __builtin_amdgcn_mfma_f32_16x16x32_bf16((a), (b), (c), 0, 0, 0)

// async global->LDS, 16B per lane. LDS dest must be wave-uniform base + lane*16.
#define GLL(g, l) __builtin_amdgcn_global_load_lds(                                  \
    (const __attribute__((address_space(1))) void*)(g),                              \
    (__attribute__((address_space(3))) void*)(l), 16, 0, 0)

#define BB 4
#define TT 2048
#define SS 512
#define DM 1024
#define NH 16
#define HD 64

__device__ __forceinline__ unsigned short f2bh(float f) {  // native v_cvt (RTNE)
    __bf16 h = (__bf16)f;
    union { __bf16 h; unsigned short u; } v; v.h = h;
    return v.u;
}

// ---------------- fused prep: casts + weight transposes + mask expand ------------
__device__ __forceinline__ void tcast_tile(const float* __restrict__ in,
                                           unsigned short* __restrict__ out,
                                           int K, int N, int n0, int k0,
                                           float (*tile)[33], int tid) {
    int tx = tid & 31, ty = tid >> 5;
#pragma unroll
    for (int r = 0; r < 32; r += 8)
        tile[ty + r][tx] = in[(k0 + ty + r) * N + n0 + tx];
    __syncthreads();
    // vectorized store: each thread writes 4 consecutive u16 (8 B)
    int r2 = tid >> 3, cg = (tid & 7) * 4;
    ushort4 o;
    o.x = f2bh(tile[cg + 0][r2]);
    o.y = f2bh(tile[cg + 1][r2]);
    o.z = f2bh(tile[cg + 2][r2]);
    o.w = f2bh(tile[cg + 3][r2]);
    *(ushort4*)&out[(n0 + r2) * K + k0 + cg] = o;
}

__global__ __launch_bounds__(256)
void prep(const float4* __restrict__ x, const float4* __restrict__ ctx,
          const unsigned int* __restrict__ mw,
          const float* __restrict__ Wq, const float* __restrict__ Wkv,
          const float* __restrict__ Wp,
          ushort4* __restrict__ Xbf, ushort4* __restrict__ Cbf,
          unsigned short* __restrict__ WqT, unsigned short* __restrict__ WkvT,
          unsigned short* __restrict__ WpT, float* __restrict__ mbias) {
    __shared__ float tile[32][33];
    __shared__ int flags[2];
    const int bid = blockIdx.x, tid = threadIdx.x;
    if (bid < 8192) {
        int i = bid * 256 + tid;
        float4 v = x[i];
        ushort4 o; o.x = f2bh(v.x); o.y = f2bh(v.y); o.z = f2bh(v.z); o.w = f2bh(v.w);
        Xbf[i] = o;
    } else if (bid < 10240) {
        int i = (bid - 8192) * 256 + tid;
        float4 v = ctx[i];
        ushort4 o; o.x = f2bh(v.x); o.y = f2bh(v.y); o.z = f2bh(v.z); o.w = f2bh(v.w);
        Cbf[i] = o;
    } else if (bid < 11264) {
        int loc = bid - 10240;
        tcast_tile(Wq, WqT, DM, DM, (loc & 31) * 32, (loc >> 5) * 32, tile, tid);
    } else if (bid < 13312) {
        int loc = bid - 11264;
        tcast_tile(Wkv, WkvT, DM, 2 * DM, (loc & 63) * 32, (loc >> 6) * 32, tile, tid);
    } else if (bid < 14336) {
        int loc = bid - 13312;
        tcast_tile(Wp, WpT, DM, DM, (loc & 31) * 32, (loc >> 5) * 32, tile, tid);
    } else {
        if (tid == 0) { flags[0] = 1; flags[1] = 1; }
        __syncthreads();
        int okI = 1, okF = 1;
        for (int i = tid; i < 512; i += 256) {
            unsigned int w = mw[i];
            if (w > 1u) okI = 0;
            if (w != 0u && w != 0x3f800000u) okF = 0;
        }
        if (!okI) atomicAnd(&flags[0], 0);
        if (!okF) atomicAnd(&flags[1], 0);
        __syncthreads();
        bool wordLayout = (flags[0] != 0) || (flags[1] != 0);
        const unsigned char* mb = (const unsigned char*)mw;
        for (int s = tid; s < BB * SS; s += 256) {
            bool on = wordLayout ? (mw[s] != 0u) : (mb[s] != 0);
            mbias[s] = on ? 0.0f : -1e38f;
        }
    }
}

// ---------------- GEMM core: 256 threads, tile 128x128, BK=64 (m97 structure) -----
// 4 waves in 2x2 grid, each owns a 64x64 output quadrant (acc[4][4] of f32x4).
// LDS XOR-swizzled in 16B pieces: As[r][p] holds source piece p^(r&7).
__device__ __forceinline__ void gemm_core(
    const unsigned short* __restrict__ A, const unsigned short* __restrict__ Bt,
    int K, int m0, int n0, unsigned short* As, unsigned short* Bs,
    f32x4 (*acc)[4]) {
    const int tid = threadIdx.x;
    const int l = tid & 63;
    const int quad = l >> 4, col = l & 15;
    const int w = tid >> 6;
    const int wm = (w & 1) * 64, wn = (w >> 1) * 64;
    const int arow = tid >> 3;                       // 0..31
    const int apiece = (tid & 7) ^ (arow & 7);
    const unsigned short* Ab = A + (size_t)(m0 + arow) * K + apiece * 8;
    const unsigned short* Bb = Bt + (size_t)(n0 + arow) * K + apiece * 8;

    for (int k0 = 0; k0 < K; k0 += 64) {
        __syncthreads();
#pragma unroll
        for (int g = 0; g < 4; ++g)
            GLL(Ab + k0 + g * 32 * K, &As[g * 2048 + tid * 8]);
#pragma unroll
        for (int g = 0; g < 4; ++g)
            GLL(Bb + k0 + g * 32 * K, &Bs[g * 2048 + tid * 8]);
        __syncthreads();
#pragma unroll
        for (int k32 = 0; k32 < 2; ++k32) {
            bf16x8 af[4], bfr[4];
#pragma unroll
            for (int i = 0; i < 4; i++) {
                int rr = wm + i * 16 + col;
                af[i] = *(const bf16x8*)&As[rr * 64 + (((k32 * 4 + quad) ^ (rr & 7)) * 8)];
            }
#pragma unroll
            for (int j = 0; j < 4; j++) {
                int rr = wn + j * 16 + col;
                bfr[j] = *(const bf16x8*)&Bs[rr * 64 + (((k32 * 4 + quad) ^ (rr & 7)) * 8)];
            }
#pragma unroll
            for (int i = 0; i < 4; i++)
#pragma unroll
                for (int j = 0; j < 4; j++) acc[i][j] = MFMA(af[i], bfr[j], acc[i][j]);
        }
    }
}

// ---------------- fused Q-proj + KV-proj (one launch, 768 blocks) ----------------
// XCD-locality swizzle: blocks sharing an A-strip satisfy bid % 8 == const.
__global__ __launch_bounds__(256, 3)
void gemm_qkv(const unsigned short* __restrict__ Xbf, const unsigned short* __restrict__ WqT,
              const float* __restrict__ bq, unsigned short* __restrict__ Qb,
              const unsigned short* __restrict__ Cbf, const unsigned short* __restrict__ WkvT,
              const float* __restrict__ bkv, unsigned short* __restrict__ Kb,
              unsigned short* __restrict__ Vtb) {
    __shared__ __align__(16) unsigned short As[128 * 64];
    __shared__ __align__(16) unsigned short Bs[128 * 64];
    const int tid = threadIdx.x;
    const int l = tid & 63;
    const int quad = l >> 4, col = l & 15;
    const int w = tid >> 6;
    const int wm = (w & 1) * 64, wn = (w >> 1) * 64;
    const int bid = blockIdx.x;

    const f32x4 zero = {0.f, 0.f, 0.f, 0.f};
    f32x4 acc[4][4];
#pragma unroll
    for (int i = 0; i < 4; i++)
#pragma unroll
        for (int j = 0; j < 4; j++) acc[i][j] = zero;

    if (bid < 512) {                        // ---- Q-proj: M=8192 (64 strips), N=1024 ----
        const int xg = bid & 7, t = bid >> 3;
        const int m0 = (xg + 8 * (t & 7)) * 128;   // same-m0 blocks -> same XCD
        const int n0 = (t >> 3) * 128;
        gemm_core(Xbf, WqT, DM, m0, n0, As, Bs, acc);
        const float QS = 0.125f * 1.4426950408889634f;  // 1/sqrt(Hd) * log2(e)
#pragma unroll
        for (int i = 0; i < 4; i++) {
#pragma unroll
            for (int j = 0; j < 4; j++) {
                int n = n0 + wn + j * 16 + col;
                int mb = m0 + wm + i * 16 + quad * 4;
                float bv = bq[n];
#pragma unroll
                for (int ii = 0; ii < 4; ii++)
                    Qb[(mb + ii) * DM + n] = f2bh((acc[i][j][ii] + bv) * QS);
            }
        }
    } else {                                // ---- KV-proj: M=2048 (16 strips), N=2048 ----
        const int loc = bid - 512;
        const int xg = loc & 7, t = loc >> 3;
        const int m0 = (xg + 8 * (t & 1)) * 128;
        const int n0 = (t >> 1) * 128;
        gemm_core(Cbf, WkvT, DM, m0, n0, As, Bs, acc);
#pragma unroll
        for (int i = 0; i < 4; i++) {
#pragma unroll
            for (int j = 0; j < 4; j++) {
                int n = n0 + wn + j * 16 + col;
                int mb = m0 + wm + i * 16 + quad * 4;
                float bv = bkv[n];
                if (n < 1024) {
                    int h = n >> 6, d = n & 63;
#pragma unroll
                    for (int ii = 0; ii < 4; ii++) {
                        int m = mb + ii; int b = m >> 9, s = m & 511;
                        Kb[(((b * NH + h) * SS) + s) * HD + d] = f2bh(acc[i][j][ii] + bv);
                    }
                } else {
                    int q = n - 1024; int h = q >> 6, d = q & 63;
#pragma unroll
                    for (int ii = 0; ii < 4; ii++) {
                        int m = mb + ii; int b = m >> 9, s = m & 511;
                        Vtb[(((b * NH + h) * HD) + d) * SS + s] = f2bh(acc[i][j][ii] + bv);
                    }
                }
            }
        }
    }
}

// ---------------- out-proj: O@Wp + bp -> f32 ----------------
__global__ __launch_bounds__(256, 3)
void gemm_out(const unsigned short* __restrict__ Ob, const unsigned short* __restrict__ WpT,
              const float* __restrict__ bp, float* __restrict__ out) {
    __shared__ __align__(16) unsigned short As[128 * 64];
    __shared__ __align__(16) unsigned short Bs[128 * 64];
    const int tid = threadIdx.x;
    const int l = tid & 63;
    const int quad = l >> 4, col = l & 15;
    const int w = tid >> 6;
    const int wm = (w & 1) * 64, wn = (w >> 1) * 64;
    const int bid = blockIdx.x;
    const int xg = bid & 7, t = bid >> 3;
    const int m0 = (xg + 8 * (t & 7)) * 128;       // XCD-locality swizzle
    const int n0 = (t >> 3) * 128;

    const f32x4 zero = {0.f, 0.f, 0.f, 0.f};
    f32x4 acc[4][4];
#pragma unroll
    for (int i = 0; i < 4; i++)
#pragma unroll
        for (int j = 0; j < 4; j++) acc[i][j] = zero;

    gemm_core(Ob, WpT, DM, m0, n0, As, Bs, acc);

#pragma unroll
    for (int i = 0; i < 4; i++) {
#pragma unroll
        for (int j = 0; j < 4; j++) {
            int n = n0 + wn + j * 16 + col;
            int mb = m0 + wm + i * 16 + quad * 4;
            float bv = bp[n];
#pragma unroll
            for (int ii = 0; ii < 4; ii++)
                out[(mb + ii) * DM + n] = acc[i][j][ii] + bv;
        }
    }
}

// ---------------- flash attention: 512 threads, Q-tile 256, S-chunk 64 ------------
// Pipelined: QK^T+softmax for BOTH 32-s halves first (P double-buffered per wave),
// then both PV halves — hides the P LDS store->load latency without lgkmcnt(0).
// lsum computed on the MFMA pipe via a ones-B fragment (same C layout as o).
__global__ __launch_bounds__(512, 4)
void flash_attn(const unsigned short* __restrict__ Q, const unsigned short* __restrict__ Kb,
                const unsigned short* __restrict__ Vt, const float* __restrict__ mbias,
                unsigned short* __restrict__ O) {
    const int bid = blockIdx.x;
    const int xg = bid & 7, tq = bid >> 3;
    const int tb = tq & 7;                 // T-tile within (b,h)
    const int bh = xg + 8 * (tq >> 3);     // same bh -> same XCD
    const int b = bh >> 4;
    const int tid = threadIdx.x;
    const int w = tid >> 6, l = tid & 63;
    const int quad = l >> 4, col = l & 15;

    __shared__ __align__(16) unsigned short Ks[2][64 * 64];   // [s][d], piece-swizzled
    __shared__ __align__(16) unsigned short Vs[2][64 * 64];   // [d][s], piece-swizzled
    __shared__ __align__(16) unsigned short Pb[8][2][32 * 32]; // per-wave, piece-XOR swizzle
    __shared__ float biasS[SS];

    const unsigned short* Kh = Kb + bh * SS * HD;
    const unsigned short* Vh = Vt + bh * HD * SS;

    float bval = mbias[b * SS + tid];      // SS==512==blockDim
    biasS[tid] = bval;
    const int allon = __syncthreads_and(bval == 0.0f);  // barrier: biasS visible below

    const int rowbase = b * TT + tb * 256 + w * 32;
    bf16x8 qf[2][2];
#pragma unroll
    for (int rg = 0; rg < 2; rg++) {
        const unsigned short* qrow = Q + (rowbase + rg * 16 + col) * DM + (bh & 15) * HD;
        qf[rg][0] = *(const bf16x8*)(qrow + quad * 8);
        qf[rg][1] = *(const bf16x8*)(qrow + 32 + quad * 8);
    }

    const int sr = tid >> 3, sp = tid & 7;
    const int spk = ((sp ^ (sr & 7)) * 8);
    const int kgo = sr * HD + spk;
    const int vgo = sr * SS + spk;

    GLL(Kh + kgo, &Ks[0][tid * 8]);
    GLL(Vh + vgo, &Vs[0][tid * 8]);

    const f32x4 zero = {0.f, 0.f, 0.f, 0.f};
    f32x4 o[2][4];
#pragma unroll
    for (int rg = 0; rg < 2; rg++)
#pragma unroll
        for (int j = 0; j < 4; j++) o[rg][j] = zero;
    f32x4 lacc[2] = {zero, zero};
    bf16x8 onesb;
#pragma unroll
    for (int z = 0; z < 8; z++) onesb[z] = (__bf16)1.0f;

    for (int it = 0; it < SS / 64; ++it) {
        const int s0 = it * 64;
        const int buf = it & 1;
        __syncthreads();
        if (it + 1 < SS / 64) {
            GLL(Kh + (s0 + 64) * HD + kgo, &Ks[buf ^ 1][tid * 8]);
            GLL(Vh + (s0 + 64) + vgo, &Vs[buf ^ 1][tid * 8]);
        }

        // ---- phase 1: QK^T + softmax for both halves; store P (double-buffered) ----
#pragma unroll
        for (int h2 = 0; h2 < 2; ++h2) {
            f32x4 sc[2][2];
#pragma unroll
            for (int jj = 0; jj < 2; ++jj) {
                int row = (2 * h2 + jj) * 16 + col;
                bf16x8 k0 = *(const bf16x8*)&Ks[buf][row * 64 + ((quad ^ (row & 7)) * 8)];
                bf16x8 k1 = *(const bf16x8*)&Ks[buf][row * 64 + (((4 + quad) ^ (row & 7)) * 8)];
                __builtin_amdgcn_s_setprio(1);
#pragma unroll
                for (int rg = 0; rg < 2; rg++) {
                    f32x4 tt = MFMA(qf[rg][0], k0, zero);
                    sc[rg][jj] = MFMA(qf[rg][1], k1, tt);
                }
                __builtin_amdgcn_s_setprio(0);
            }
            if (allon) {
#pragma unroll
                for (int rg = 0; rg < 2; rg++)
#pragma unroll
                    for (int jj = 0; jj < 2; jj++)
#pragma unroll
                        for (int i = 0; i < 4; i++) {
                            float p = exp2f(sc[rg][jj][i]);
                            int row = rg * 16 + quad * 4 + i;
                            int s = jj * 16 + col;
                            int pc = (s >> 3) ^ ((row >> 1) & 3);
                            Pb[w][h2][(row << 5) + (pc << 3) + (s & 7)] = f2bh(p);
                        }
            } else {
#pragma unroll
                for (int rg = 0; rg < 2; rg++)
#pragma unroll
                    for (int jj = 0; jj < 2; jj++) {
                        float bb = biasS[s0 + (2 * h2 + jj) * 16 + col];
#pragma unroll
                        for (int i = 0; i < 4; i++) {
                            float p = exp2f(sc[rg][jj][i] + bb);
                            int row = rg * 16 + quad * 4 + i;
                            int s = jj * 16 + col;
                            int pc = (s >> 3) ^ ((row >> 1) & 3);
                            Pb[w][h2][(row << 5) + (pc << 3) + (s & 7)] = f2bh(p);
                        }
                    }
            }
        }

        // ---- phase 2: PV (+ lsum via MFMA) for both halves ----
#pragma unroll
        for (int h2 = 0; h2 < 2; ++h2) {
            bf16x8 pf[2];
#pragma unroll
            for (int rg = 0; rg < 2; rg++) {
                int prow = rg * 16 + col;
                int pp = quad ^ ((col >> 1) & 3);
                pf[rg] = *(const bf16x8*)&Pb[w][h2][(prow << 5) + (pp << 3)];
            }
            __builtin_amdgcn_s_setprio(1);
#pragma unroll
            for (int rg = 0; rg < 2; rg++) lacc[rg] = MFMA(pf[rg], onesb, lacc[rg]);
#pragma unroll
            for (int j2 = 0; j2 < 4; j2++) {
                int row = j2 * 16 + col;
                bf16x8 vf = *(const bf16x8*)&Vs[buf][row * 64 + (((h2 * 4 + quad) ^ (row & 7)) * 8)];
#pragma unroll
                for (int rg = 0; rg < 2; rg++)
                    o[rg][j2] = MFMA(pf[rg], vf, o[rg][j2]);
            }
            __builtin_amdgcn_s_setprio(0);
        }
    }

#pragma unroll
    for (int rg = 0; rg < 2; rg++) {
#pragma unroll
        for (int i = 0; i < 4; i++) {
            float inv = 1.0f / lacc[rg][i];
            unsigned short* orow = O + (rowbase + rg * 16 + quad * 4 + i) * DM
                                     + (bh & 15) * HD + col;
#pragma unroll
            for (int j2 = 0; j2 < 4; j2++)
                orow[j2 * 16] = f2bh(o[rg][j2][i] * inv);
        }
    }
}

// ---------------- launcher ----------------
extern "C" void kernel_launch(void* const* d_in, const int* in_sizes, int n_in,
                              void* d_out, int out_size, void* d_ws, size_t ws_size,
                              hipStream_t stream) {
    const float* x    = (const float*)d_in[0];
    const float* ctx  = (const float*)d_in[1];
    const void*  cmsk = d_in[2];
    const float* Wq   = (const float*)d_in[3];
    const float* bq   = (const float*)d_in[4];
    const float* Wkv  = (const float*)d_in[5];
    const float* bkv  = (const float*)d_in[6];
    const float* Wp   = (const float*)d_in[7];
    const float* bp   = (const float*)d_in[8];
    float* out = (float*)d_out;

    char* ws = (char*)d_ws;
    size_t off = 0;
    auto alloc = [&](size_t bytes) -> void* {
        void* p = ws + off;
        off += (bytes + 255) & ~(size_t)255;
        return p;
    };
    const size_t NX = (size_t)BB * TT * DM;   // 8388608
    const size_t NC = (size_t)BB * SS * DM;   // 2097152
    unsigned short* Xbf  = (unsigned short*)alloc(NX * 2);
    unsigned short* Cbf  = (unsigned short*)alloc(NC * 2);
    unsigned short* WqT  = (unsigned short*)alloc((size_t)DM * DM * 2);
    unsigned short* WkvT = (unsigned short*)alloc((size_t)DM * 2 * DM * 2);
    unsigned short* WpT  = (unsigned short*)alloc((size_t)DM * DM * 2);
    unsigned short* Qb   = (unsigned short*)alloc(NX * 2);
    unsigned short* Kbf  = (unsigned short*)alloc(NC * 2);
    unsigned short* Vtb  = (unsigned short*)alloc(NC * 2);
    unsigned short* Ob   = (unsigned short*)alloc(NX * 2);
    float* mbias         = (float*)alloc((size_t)BB * SS * 4);

    prep<<<14337, 256, 0, stream>>>((const float4*)x, (const float4*)ctx,
                                    (const unsigned int*)cmsk, Wq, Wkv, Wp,
                                    (ushort4*)Xbf, (ushort4*)Cbf,
                                    WqT, WkvT, WpT, mbias);

    // Q-proj + KV-proj fused in one launch (512 + 256 blocks, 128x128 tiles)
    gemm_qkv<<<768, 256, 0, stream>>>(Xbf, WqT, bq, Qb, Cbf, WkvT, bkv, Kbf, Vtb);

    // attention
    flash_attn<<<BB * NH * (TT / 256), 512, 0, stream>>>(Qb, Kbf, Vtb, mbias, Ob);

    // out = O@Wp + bp (fp32)
    gemm_out<<<512, 256, 0, stream>>>(Ob, WpT, bp, out);
}

// Round 4
// 200.351 us; speedup vs baseline: 1.0428x; 1.0428x over previous
//
#include <hip/hip_runtime.h>

// ---------------- types / helpers ----------------
typedef __bf16 bf16x8 __attribute__((ext_vector_type(8)));
typedef float  f32x4  __attribute__((ext_vector_type(4)));
typedef float  f32x16 __attribute__((ext_vector_type(16)));
typedef unsigned int u32x2 __attribute__((ext_vector_type(2)));

#define MFMA(a, b, c)   __builtin_amdgcn_mfma_f32_16x16x32_bf16((a), (b), (c), 0, 0, 0)
#define MFMA32(a, b, c) __builtin_amdgcn_mfma_f32_32x32x16_bf16((a), (b), (c), 0, 0, 0)

// async global->LDS, 16B per lane. LDS dest must be wave-uniform base + lane*16.
#define GLL(g, l) __builtin_amdgcn_global_load_lds(                                  \
    (const __attribute__((address_space(1))) void*)(g),                              \
    (__attribute__((address_space(3))) void*)(l), 16, 0, 0)

#define BB 4
#define TT 2048
#define SS 512
#define DM 1024
#define NH 16
#define HD 64

__device__ __forceinline__ unsigned short f2bh(float f) {  // native v_cvt (RTNE)
    __bf16 h = (__bf16)f;
    union { __bf16 h; unsigned short u; } v; v.h = h;
    return v.u;
}

__device__ __forceinline__ unsigned int pk2(float a, float b) {  // (lo,hi) bf16 pair
    return (unsigned int)f2bh(a) | ((unsigned int)f2bh(b) << 16);
}

// v_permlane32_swap_b32: new_a = {a.lanes[0:31], b.lanes[0:31]},
//                        new_b = {a.lanes[32:63], b.lanes[32:63]}
__device__ __forceinline__ void pl32swap(unsigned int& a, unsigned int& b) {
    u32x2 r = __builtin_amdgcn_permlane32_swap(a, b, false, false);
    a = r[0]; b = r[1];
}

// ---------------- fused prep: casts + weight transposes + mask expand ------------
__device__ __forceinline__ void tcast_tile(const float* __restrict__ in,
                                           unsigned short* __restrict__ out,
                                           int K, int N, int n0, int k0,
                                           float (*tile)[33], int tid) {
    int tx = tid & 31, ty = tid >> 5;
#pragma unroll
    for (int r = 0; r < 32; r += 8)
        tile[ty + r][tx] = in[(k0 + ty + r) * N + n0 + tx];
    __syncthreads();
    // vectorized store: each thread writes 4 consecutive u16 (8 B)
    int r2 = tid >> 3, cg = (tid & 7) * 4;
    ushort4 o;
    o.x = f2bh(tile[cg + 0][r2]);
    o.y = f2bh(tile[cg + 1][r2]);
    o.z = f2bh(tile[cg + 2][r2]);
    o.w = f2bh(tile[cg + 3][r2]);
    *(ushort4*)&out[(n0 + r2) * K + k0 + cg] = o;
}

__global__ __launch_bounds__(256)
void prep(const float4* __restrict__ x, const float4* __restrict__ ctx,
          const unsigned int* __restrict__ mw,
          const float* __restrict__ Wq, const float* __restrict__ Wkv,
          const float* __restrict__ Wp,
          ushort4* __restrict__ Xbf, ushort4* __restrict__ Cbf,
          unsigned short* __restrict__ WqT, unsigned short* __restrict__ WkvT,
          unsigned short* __restrict__ WpT, float* __restrict__ mbias) {
    __shared__ float tile[32][33];
    __shared__ int flags[2];
    const int bid = blockIdx.x, tid = threadIdx.x;
    if (bid < 8192) {
        int i = bid * 256 + tid;
        float4 v = x[i];
        ushort4 o; o.x = f2bh(v.x); o.y = f2bh(v.y); o.z = f2bh(v.z); o.w = f2bh(v.w);
        Xbf[i] = o;
    } else if (bid < 10240) {
        int i = (bid - 8192) * 256 + tid;
        float4 v = ctx[i];
        ushort4 o; o.x = f2bh(v.x); o.y = f2bh(v.y); o.z = f2bh(v.z); o.w = f2bh(v.w);
        Cbf[i] = o;
    } else if (bid < 11264) {
        int loc = bid - 10240;
        tcast_tile(Wq, WqT, DM, DM, (loc & 31) * 32, (loc >> 5) * 32, tile, tid);
    } else if (bid < 13312) {
        int loc = bid - 11264;
        tcast_tile(Wkv, WkvT, DM, 2 * DM, (loc & 63) * 32, (loc >> 6) * 32, tile, tid);
    } else if (bid < 14336) {
        int loc = bid - 13312;
        tcast_tile(Wp, WpT, DM, DM, (loc & 31) * 32, (loc >> 5) * 32, tile, tid);
    } else {
        if (tid == 0) { flags[0] = 1; flags[1] = 1; }
        __syncthreads();
        int okI = 1, okF = 1;
        for (int i = tid; i < 512; i += 256) {
            unsigned int w = mw[i];
            if (w > 1u) okI = 0;
            if (w != 0u && w != 0x3f800000u) okF = 0;
        }
        if (!okI) atomicAnd(&flags[0], 0);
        if (!okF) atomicAnd(&flags[1], 0);
        __syncthreads();
        bool wordLayout = (flags[0] != 0) || (flags[1] != 0);
        const unsigned char* mb = (const unsigned char*)mw;
        for (int s = tid; s < BB * SS; s += 256) {
            bool on = wordLayout ? (mw[s] != 0u) : (mb[s] != 0);
            mbias[s] = on ? 0.0f : -1e38f;
        }
    }
}

// ---------------- GEMM core: 256 threads, tile 128x128, BK=64 (m97 structure) -----
__device__ __forceinline__ void gemm_core(
    const unsigned short* __restrict__ A, const unsigned short* __restrict__ Bt,
    int K, int m0, int n0, unsigned short* As, unsigned short* Bs,
    f32x4 (*acc)[4]) {
    const int tid = threadIdx.x;
    const int l = tid & 63;
    const int quad = l >> 4, col = l & 15;
    const int w = tid >> 6;
    const int wm = (w & 1) * 64, wn = (w >> 1) * 64;
    const int arow = tid >> 3;                       // 0..31
    const int apiece = (tid & 7) ^ (arow & 7);
    const unsigned short* Ab = A + (size_t)(m0 + arow) * K + apiece * 8;
    const unsigned short* Bb = Bt + (size_t)(n0 + arow) * K + apiece * 8;

    for (int k0 = 0; k0 < K; k0 += 64) {
        __syncthreads();
#pragma unroll
        for (int g = 0; g < 4; ++g)
            GLL(Ab + k0 + g * 32 * K, &As[g * 2048 + tid * 8]);
#pragma unroll
        for (int g = 0; g < 4; ++g)
            GLL(Bb + k0 + g * 32 * K, &Bs[g * 2048 + tid * 8]);
        __syncthreads();
#pragma unroll
        for (int k32 = 0; k32 < 2; ++k32) {
            bf16x8 af[4], bfr[4];
#pragma unroll
            for (int i = 0; i < 4; i++) {
                int rr = wm + i * 16 + col;
                af[i] = *(const bf16x8*)&As[rr * 64 + (((k32 * 4 + quad) ^ (rr & 7)) * 8)];
            }
#pragma unroll
            for (int j = 0; j < 4; j++) {
                int rr = wn + j * 16 + col;
                bfr[j] = *(const bf16x8*)&Bs[rr * 64 + (((k32 * 4 + quad) ^ (rr & 7)) * 8)];
            }
#pragma unroll
            for (int i = 0; i < 4; i++)
#pragma unroll
                for (int j = 0; j < 4; j++) acc[i][j] = MFMA(af[i], bfr[j], acc[i][j]);
        }
    }
}

// ---------------- fused Q-proj + KV-proj (one launch, 768 blocks) ----------------
__global__ __launch_bounds__(256, 3)
void gemm_qkv(const unsigned short* __restrict__ Xbf, const unsigned short* __restrict__ WqT,
              const float* __restrict__ bq, unsigned short* __restrict__ Qb,
              const unsigned short* __restrict__ Cbf, const unsigned short* __restrict__ WkvT,
              const float* __restrict__ bkv, unsigned short* __restrict__ Kb,
              unsigned short* __restrict__ Vtb) {
    __shared__ __align__(16) unsigned short As[128 * 64];
    __shared__ __align__(16) unsigned short Bs[128 * 64];
    const int tid = threadIdx.x;
    const int l = tid & 63;
    const int quad = l >> 4, col = l & 15;
    const int w = tid >> 6;
    const int wm = (w & 1) * 64, wn = (w >> 1) * 64;
    const int bid = blockIdx.x;

    const f32x4 zero = {0.f, 0.f, 0.f, 0.f};
    f32x4 acc[4][4];
#pragma unroll
    for (int i = 0; i < 4; i++)
#pragma unroll
        for (int j = 0; j < 4; j++) acc[i][j] = zero;

    if (bid < 512) {                        // ---- Q-proj: M=8192 (64 strips), N=1024 ----
        const int xg = bid & 7, t = bid >> 3;
        const int m0 = (xg + 8 * (t & 7)) * 128;   // same-m0 blocks -> same XCD
        const int n0 = (t >> 3) * 128;
        gemm_core(Xbf, WqT, DM, m0, n0, As, Bs, acc);
        const float QS = 0.125f * 1.4426950408889634f;  // 1/sqrt(Hd) * log2(e)
#pragma unroll
        for (int i = 0; i < 4; i++) {
#pragma unroll
            for (int j = 0; j < 4; j++) {
                int n = n0 + wn + j * 16 + col;
                int mb = m0 + wm + i * 16 + quad * 4;
                float bv = bq[n];
#pragma unroll
                for (int ii = 0; ii < 4; ii++)
                    Qb[(mb + ii) * DM + n] = f2bh((acc[i][j][ii] + bv) * QS);
            }
        }
    } else {                                // ---- KV-proj: M=2048 (16 strips), N=2048 ----
        const int loc = bid - 512;
        const int xg = loc & 7, t = loc >> 3;
        const int m0 = (xg + 8 * (t & 1)) * 128;
        const int n0 = (t >> 1) * 128;
        gemm_core(Cbf, WkvT, DM, m0, n0, As, Bs, acc);
#pragma unroll
        for (int i = 0; i < 4; i++) {
#pragma unroll
            for (int j = 0; j < 4; j++) {
                int n = n0 + wn + j * 16 + col;
                int mb = m0 + wm + i * 16 + quad * 4;
                float bv = bkv[n];
                if (n < 1024) {
                    int h = n >> 6, d = n & 63;
#pragma unroll
                    for (int ii = 0; ii < 4; ii++) {
                        int m = mb + ii; int b = m >> 9, s = m & 511;
                        Kb[(((b * NH + h) * SS) + s) * HD + d] = f2bh(acc[i][j][ii] + bv);
                    }
                } else {
                    int q = n - 1024; int h = q >> 6, d = q & 63;
#pragma unroll
                    for (int ii = 0; ii < 4; ii++) {
                        int m = mb + ii; int b = m >> 9, s = m & 511;
                        Vtb[(((b * NH + h) * HD) + d) * SS + s] = f2bh(acc[i][j][ii] + bv);
                    }
                }
            }
        }
    }
}

// ---------------- out-proj: O@Wp + bp -> f32 ----------------
__global__ __launch_bounds__(256, 3)
void gemm_out(const unsigned short* __restrict__ Ob, const unsigned short* __restrict__ WpT,
              const float* __restrict__ bp, float* __restrict__ out) {
    __shared__ __align__(16) unsigned short As[128 * 64];
    __shared__ __align__(16) unsigned short Bs[128 * 64];
    const int tid = threadIdx.x;
    const int l = tid & 63;
    const int quad = l >> 4, col = l & 15;
    const int w = tid >> 6;
    const int wm = (w & 1) * 64, wn = (w >> 1) * 64;
    const int bid = blockIdx.x;
    const int xg = bid & 7, t = bid >> 3;
    const int m0 = (xg + 8 * (t & 7)) * 128;       // XCD-locality swizzle
    const int n0 = (t >> 3) * 128;

    const f32x4 zero = {0.f, 0.f, 0.f, 0.f};
    f32x4 acc[4][4];
#pragma unroll
    for (int i = 0; i < 4; i++)
#pragma unroll
        for (int j = 0; j < 4; j++) acc[i][j] = zero;

    gemm_core(Ob, WpT, DM, m0, n0, As, Bs, acc);

#pragma unroll
    for (int i = 0; i < 4; i++) {
#pragma unroll
        for (int j = 0; j < 4; j++) {
            int n = n0 + wn + j * 16 + col;
            int mb = m0 + wm + i * 16 + quad * 4;
            float bv = bp[n];
#pragma unroll
            for (int ii = 0; ii < 4; ii++)
                out[(mb + ii) * DM + n] = acc[i][j][ii] + bv;
        }
    }
}

// ---------------- flash attention: 512 thr, 8 waves x 32 q-rows, 32x32 MFMA -------
// Swapped QK^T: mfma(A=K, B=Q) -> C col = q (lane&31), row = s. Each lane owns ONE
// q-column; softmax is lane-local. P -> PV A-fragment built IN REGISTERS:
// pack bf16 pairs + v_permlane32_swap (T12). No P LDS round-trip; lsum is a
// lane scalar (pair-sum via shfl_xor(32), bcast via ds_bpermute).
__global__ __launch_bounds__(512, 4)
void flash_attn(const unsigned short* __restrict__ Q, const unsigned short* __restrict__ Kb,
                const unsigned short* __restrict__ Vt, const float* __restrict__ mbias,
                unsigned short* __restrict__ O) {
    const int bid = blockIdx.x;
    const int xg = bid & 7, tq = bid >> 3;
    const int tb = tq & 7;                 // T-tile within (b,h)
    const int bh = xg + 8 * (tq >> 3);     // same bh -> same XCD
    const int b = bh >> 4;
    const int tid = threadIdx.x;
    const int w = tid >> 6, l = tid & 63;
    const int lq = l & 31, hi = l >> 5;

    __shared__ __align__(16) unsigned short Ks[2][64 * 64];   // [s][d], piece-swizzled
    __shared__ __align__(16) unsigned short Vs[2][64 * 64];   // [d][s], piece-swizzled
    __shared__ float biasS[SS];

    const unsigned short* Kh = Kb + bh * SS * HD;
    const unsigned short* Vh = Vt + bh * HD * SS;

    float bval = mbias[b * SS + tid];      // SS==512==blockDim
    biasS[tid] = bval;
    const int allon = __syncthreads_and(bval == 0.0f);  // barrier: biasS visible below

    const int rowbase = b * TT + tb * 256 + w * 32;
    const int hd0 = (bh & 15) * HD;

    // Q fragments: B-operand, lane holds q = lq, k(d)-slice = 16*ch + 8*hi .. +8
    const unsigned short* qrow = Q + (size_t)(rowbase + lq) * DM + hd0;
    bf16x8 qf[4];
#pragma unroll
    for (int ch = 0; ch < 4; ++ch)
        qf[ch] = *(const bf16x8*)(qrow + ch * 16 + hi * 8);

    const int sr = tid >> 3, sp = tid & 7;
    const int spk = ((sp ^ (sr & 7)) * 8);
    const int kgo = sr * HD + spk;
    const int vgo = sr * SS + spk;

    GLL(Kh + kgo, &Ks[0][tid * 8]);
    GLL(Vh + vgo, &Vs[0][tid * 8]);

    const f32x16 zero16 = {0.f,0.f,0.f,0.f,0.f,0.f,0.f,0.f,
                           0.f,0.f,0.f,0.f,0.f,0.f,0.f,0.f};
    f32x16 oacc0 = zero16, oacc1 = zero16;   // d-tiles 0..31 / 32..63
    float lsum = 0.f;

    for (int it = 0; it < SS / 64; ++it) {
        const int s0 = it * 64;
        const int buf = it & 1;
        __syncthreads();
        if (it + 1 < SS / 64) {
            GLL(Kh + (s0 + 64) * HD + kgo, &Ks[buf ^ 1][tid * 8]);
            GLL(Vh + (s0 + 64) + vgo, &Vs[buf ^ 1][tid * 8]);
        }

        // ---- QK^T: two 32-s tiles, 4 chained d-windows each ----
        f32x16 cs0 = zero16, cs1 = zero16;
        __builtin_amdgcn_s_setprio(1);
#pragma unroll
        for (int ch = 0; ch < 4; ++ch) {
            const int p0 = ((2 * ch + hi) ^ (lq & 7)) * 8;
            bf16x8 k0 = *(const bf16x8*)&Ks[buf][lq * 64 + p0];
            bf16x8 k1 = *(const bf16x8*)&Ks[buf][(lq + 32) * 64 + p0];
            cs0 = MFMA32(k0, qf[ch], cs0);
            cs1 = MFMA32(k1, qf[ch], cs1);
        }
        __builtin_amdgcn_s_setprio(0);

        // ---- softmax (lane-local) + in-register P-fragment build ----
        bf16x8 pfrag[4];
#pragma unroll
        for (int sg = 0; sg < 2; ++sg) {
            float pr[16];
#pragma unroll
            for (int r = 0; r < 16; ++r) {
                float sc = (sg == 0) ? cs0[r] : cs1[r];
                if (!allon)
                    sc += biasS[s0 + 32 * sg + ((r & 3) + 8 * (r >> 2) + 4 * hi)];
                pr[r] = exp2f(sc);
                lsum += pr[r];
            }
            unsigned int wd0 = pk2(pr[0], pr[1]),  wd1 = pk2(pr[2], pr[3]);
            unsigned int wd2 = pk2(pr[4], pr[5]),  wd3 = pk2(pr[6], pr[7]);
            unsigned int wd4 = pk2(pr[8], pr[9]),  wd5 = pk2(pr[10], pr[11]);
            unsigned int wd6 = pk2(pr[12], pr[13]), wd7 = pk2(pr[14], pr[15]);
            pl32swap(wd0, wd2); pl32swap(wd1, wd3);
            pl32swap(wd4, wd6); pl32swap(wd5, wd7);
            union { unsigned int u[4]; bf16x8 v; } f0, f1;
            f0.u[0] = wd0; f0.u[1] = wd1; f0.u[2] = wd2; f0.u[3] = wd3;
            f1.u[0] = wd4; f1.u[1] = wd5; f1.u[2] = wd6; f1.u[3] = wd7;
            pfrag[2 * sg + 0] = f0.v;
            pfrag[2 * sg + 1] = f1.v;
        }

        // ---- PV: O[q][d] += P[q][s] * V[s][d]; 2 d-tiles x 4 s-windows ----
        __builtin_amdgcn_s_setprio(1);
#pragma unroll
        for (int win = 0; win < 4; ++win) {
            const int pv0 = ((2 * win + hi) ^ (lq & 7)) * 8;
            bf16x8 v0 = *(const bf16x8*)&Vs[buf][lq * 64 + pv0];
            bf16x8 v1 = *(const bf16x8*)&Vs[buf][(lq + 32) * 64 + pv0];
            oacc0 = MFMA32(pfrag[win], v0, oacc0);
            oacc1 = MFMA32(pfrag[win], v1, oacc1);
        }
        __builtin_amdgcn_s_setprio(0);
    }

    // ---- epilogue: lsum total per q, broadcast inverse, scaled bf16 store ----
    lsum += __shfl_xor(lsum, 32);
    float inv = 1.0f / lsum;               // lane lq (hi=0/1) holds inv for q == lq
    union { float f; int i; } cv; cv.f = inv;
#pragma unroll
    for (int r = 0; r < 16; ++r) {
        const int qloc = (r & 3) + 8 * (r >> 2) + 4 * hi;
        union { int i; float f; } rv;
        rv.i = __builtin_amdgcn_ds_bpermute(4 * qloc, cv.i);
        const float iq = rv.f;
        unsigned short* orow = O + (size_t)(rowbase + qloc) * DM + hd0 + lq;
        orow[0]  = f2bh(oacc0[r] * iq);
        orow[32] = f2bh(oacc1[r] * iq);
    }
}

// ---------------- launcher ----------------
extern "C" void kernel_launch(void* const* d_in, const int* in_sizes, int n_in,
                              void* d_out, int out_size, void* d_ws, size_t ws_size,
                              hipStream_t stream) {
    const float* x    = (const float*)d_in[0];
    const float* ctx  = (const float*)d_in[1];
    const void*  cmsk = d_in[2];
    const float* Wq   = (const float*)d_in[3];
    const float* bq   = (const float*)d_in[4];
    const float* Wkv  = (const float*)d_in[5];
    const float* bkv  = (const float*)d_in[6];
    const float* Wp   = (const float*)d_in[7];
    const float* bp   = (const float*)d_in[8];
    float* out = (float*)d_out;

    char* ws = (char*)d_ws;
    size_t off = 0;
    auto alloc = [&](size_t bytes) -> void* {
        void* p = ws + off;
        off += (bytes + 255) & ~(size_t)255;
        return p;
    };
    const size_t NX = (size_t)BB * TT * DM;   // 8388608
    const size_t NC = (size_t)BB * SS * DM;   // 2097152
    unsigned short* Xbf  = (unsigned short*)alloc(NX * 2);
    unsigned short* Cbf  = (unsigned short*)alloc(NC * 2);
    unsigned short* WqT  = (unsigned short*)alloc((size_t)DM * DM * 2);
    unsigned short* WkvT = (unsigned short*)alloc((size_t)DM * 2 * DM * 2);
    unsigned short* WpT  = (unsigned short*)alloc((size_t)DM * DM * 2);
    unsigned short* Qb   = (unsigned short*)alloc(NX * 2);
    unsigned short* Kbf  = (unsigned short*)alloc(NC * 2);
    unsigned short* Vtb  = (unsigned short*)alloc(NC * 2);
    unsigned short* Ob   = (unsigned short*)alloc(NX * 2);
    float* mbias         = (float*)alloc((size_t)BB * SS * 4);

    prep<<<14337, 256, 0, stream>>>((const float4*)x, (const float4*)ctx,
                                    (const unsigned int*)cmsk, Wq, Wkv, Wp,
                                    (ushort4*)Xbf, (ushort4*)Cbf,
                                    WqT, WkvT, WpT, mbias);

    // Q-proj + KV-proj fused in one launch (512 + 256 blocks, 128x128 tiles)
    gemm_qkv<<<768, 256, 0, stream>>>(Xbf, WqT, bq, Qb, Cbf, WkvT, bkv, Kbf, Vtb);

    // attention
    flash_attn<<<BB * NH * (TT / 256), 512, 0, stream>>>(Qb, Kbf, Vtb, mbias, Ob);

    // out = O@Wp + bp (fp32)
    gemm_out<<<512, 256, 0, stream>>>(Ob, WpT, bp, out);
}

// Round 6
// 195.137 us; speedup vs baseline: 1.0707x; 1.0267x over previous
//
#include <hip/hip_runtime.h>

// ---------------- types / helpers ----------------
typedef __bf16 bf16x8 __attribute__((ext_vector_type(8)));
typedef float  f32x4  __attribute__((ext_vector_type(4)));
typedef float  f32x16 __attribute__((ext_vector_type(16)));
typedef unsigned int u32x2 __attribute__((ext_vector_type(2)));

#define MFMA(a, b, c)   __builtin_amdgcn_mfma_f32_16x16x32_bf16((a), (b), (c), 0, 0, 0)
#define MFMA32(a, b, c) __builtin_amdgcn_mfma_f32_32x32x16_bf16((a), (b), (c), 0, 0, 0)

// async global->LDS, 16B per lane. LDS dest must be wave-uniform base + lane*16.
#define GLL(g, l) __builtin_amdgcn_global_load_lds(                                  \
    (const __attribute__((address_space(1))) void*)(g),                              \
    (__attribute__((address_space(3))) void*)(l), 16, 0, 0)

#define BB 4
#define TT 2048
#define SS 512
#define DM 1024
#define NH 16
#define HD 64

__device__ __forceinline__ unsigned short f2bh(float f) {  // native v_cvt (RTNE)
    __bf16 h = (__bf16)f;
    union { __bf16 h; unsigned short u; } v; v.h = h;
    return v.u;
}

__device__ __forceinline__ unsigned int pk2(float a, float b) {  // (lo,hi) bf16 pair
    return (unsigned int)f2bh(a) | ((unsigned int)f2bh(b) << 16);
}

// v_permlane32_swap_b32: new_a = {a.lanes[0:31], b.lanes[0:31]},
//                        new_b = {a.lanes[32:63], b.lanes[32:63]}
__device__ __forceinline__ void pl32swap(unsigned int& a, unsigned int& b) {
    u32x2 r = __builtin_amdgcn_permlane32_swap(a, b, false, false);
    a = r[0]; b = r[1];
}

__device__ __forceinline__ float fexp2(float x) {  // raw v_exp_f32 (2^x)
    float e;
    asm("v_exp_f32 %0, %1" : "=v"(e) : "v"(x));
    return e;
}

// ---------------- fused prep: casts + weight transposes + mask expand ------------
__device__ __forceinline__ void tcast_tile(const float* __restrict__ in,
                                           unsigned short* __restrict__ out,
                                           int K, int N, int n0, int k0,
                                           float (*tile)[33], int tid) {
    int tx = tid & 31, ty = tid >> 5;
#pragma unroll
    for (int r = 0; r < 32; r += 8)
        tile[ty + r][tx] = in[(k0 + ty + r) * N + n0 + tx];
    __syncthreads();
    // vectorized store: each thread writes 4 consecutive u16 (8 B)
    int r2 = tid >> 3, cg = (tid & 7) * 4;
    ushort4 o;
    o.x = f2bh(tile[cg + 0][r2]);
    o.y = f2bh(tile[cg + 1][r2]);
    o.z = f2bh(tile[cg + 2][r2]);
    o.w = f2bh(tile[cg + 3][r2]);
    *(ushort4*)&out[(n0 + r2) * K + k0 + cg] = o;
}

__global__ __launch_bounds__(256)
void prep(const float4* __restrict__ x, const float4* __restrict__ ctx,
          const unsigned int* __restrict__ mw,
          const float* __restrict__ Wq, const float* __restrict__ Wkv,
          const float* __restrict__ Wp,
          ushort4* __restrict__ Xbf, ushort4* __restrict__ Cbf,
          unsigned short* __restrict__ WqT, unsigned short* __restrict__ WkvT,
          unsigned short* __restrict__ WpT, float* __restrict__ mbias) {
    __shared__ float tile[32][33];
    __shared__ int flags[2];
    const int bid = blockIdx.x, tid = threadIdx.x;
    if (bid < 8192) {
        int i = bid * 256 + tid;
        float4 v = x[i];
        ushort4 o; o.x = f2bh(v.x); o.y = f2bh(v.y); o.z = f2bh(v.z); o.w = f2bh(v.w);
        Xbf[i] = o;
    } else if (bid < 10240) {
        int i = (bid - 8192) * 256 + tid;
        float4 v = ctx[i];
        ushort4 o; o.x = f2bh(v.x); o.y = f2bh(v.y); o.z = f2bh(v.z); o.w = f2bh(v.w);
        Cbf[i] = o;
    } else if (bid < 11264) {
        int loc = bid - 10240;
        tcast_tile(Wq, WqT, DM, DM, (loc & 31) * 32, (loc >> 5) * 32, tile, tid);
    } else if (bid < 13312) {
        int loc = bid - 11264;
        tcast_tile(Wkv, WkvT, DM, 2 * DM, (loc & 63) * 32, (loc >> 6) * 32, tile, tid);
    } else if (bid < 14336) {
        int loc = bid - 13312;
        tcast_tile(Wp, WpT, DM, DM, (loc & 31) * 32, (loc >> 5) * 32, tile, tid);
    } else {
        if (tid == 0) { flags[0] = 1; flags[1] = 1; }
        __syncthreads();
        int okI = 1, okF = 1;
        for (int i = tid; i < 512; i += 256) {
            unsigned int w = mw[i];
            if (w > 1u) okI = 0;
            if (w != 0u && w != 0x3f800000u) okF = 0;
        }
        if (!okI) atomicAnd(&flags[0], 0);
        if (!okF) atomicAnd(&flags[1], 0);
        __syncthreads();
        bool wordLayout = (flags[0] != 0) || (flags[1] != 0);
        const unsigned char* mb = (const unsigned char*)mw;
        for (int s = tid; s < BB * SS; s += 256) {
            bool on = wordLayout ? (mw[s] != 0u) : (mb[s] != 0);
            mbias[s] = on ? 0.0f : -1e38f;
        }
    }
}

// ---------------- GEMM core: 256 threads, tile 128x128, BK=64 (m97 structure) -----
__device__ __forceinline__ void gemm_core(
    const unsigned short* __restrict__ A, const unsigned short* __restrict__ Bt,
    int K, int m0, int n0, unsigned short* As, unsigned short* Bs,
    f32x4 (*acc)[4]) {
    const int tid = threadIdx.x;
    const int l = tid & 63;
    const int quad = l >> 4, col = l & 15;
    const int w = tid >> 6;
    const int wm = (w & 1) * 64, wn = (w >> 1) * 64;
    const int arow = tid >> 3;                       // 0..31
    const int apiece = (tid & 7) ^ (arow & 7);
    const unsigned short* Ab = A + (size_t)(m0 + arow) * K + apiece * 8;
    const unsigned short* Bb = Bt + (size_t)(n0 + arow) * K + apiece * 8;

    for (int k0 = 0; k0 < K; k0 += 64) {
        __syncthreads();
#pragma unroll
        for (int g = 0; g < 4; ++g)
            GLL(Ab + k0 + g * 32 * K, &As[g * 2048 + tid * 8]);
#pragma unroll
        for (int g = 0; g < 4; ++g)
            GLL(Bb + k0 + g * 32 * K, &Bs[g * 2048 + tid * 8]);
        __syncthreads();
#pragma unroll
        for (int k32 = 0; k32 < 2; ++k32) {
            bf16x8 af[4], bfr[4];
#pragma unroll
            for (int i = 0; i < 4; i++) {
                int rr = wm + i * 16 + col;
                af[i] = *(const bf16x8*)&As[rr * 64 + (((k32 * 4 + quad) ^ (rr & 7)) * 8)];
            }
#pragma unroll
            for (int j = 0; j < 4; j++) {
                int rr = wn + j * 16 + col;
                bfr[j] = *(const bf16x8*)&Bs[rr * 64 + (((k32 * 4 + quad) ^ (rr & 7)) * 8)];
            }
#pragma unroll
            for (int i = 0; i < 4; i++)
#pragma unroll
                for (int j = 0; j < 4; j++) acc[i][j] = MFMA(af[i], bfr[j], acc[i][j]);
        }
    }
}

// ---------------- fused Q-proj + KV-proj (one launch, 768 blocks) ----------------
__global__ __launch_bounds__(256, 3)
void gemm_qkv(const unsigned short* __restrict__ Xbf, const unsigned short* __restrict__ WqT,
              const float* __restrict__ bq, unsigned short* __restrict__ Qb,
              const unsigned short* __restrict__ Cbf, const unsigned short* __restrict__ WkvT,
              const float* __restrict__ bkv, unsigned short* __restrict__ Kb,
              unsigned short* __restrict__ Vtb) {
    __shared__ __align__(16) unsigned short As[128 * 64];
    __shared__ __align__(16) unsigned short Bs[128 * 64];
    const int tid = threadIdx.x;
    const int l = tid & 63;
    const int quad = l >> 4, col = l & 15;
    const int w = tid >> 6;
    const int wm = (w & 1) * 64, wn = (w >> 1) * 64;
    const int bid = blockIdx.x;

    const f32x4 zero = {0.f, 0.f, 0.f, 0.f};
    f32x4 acc[4][4];
#pragma unroll
    for (int i = 0; i < 4; i++)
#pragma unroll
        for (int j = 0; j < 4; j++) acc[i][j] = zero;

    if (bid < 512) {                        // ---- Q-proj: M=8192 (64 strips), N=1024 ----
        const int xg = bid & 7, t = bid >> 3;
        const int m0 = (xg + 8 * (t & 7)) * 128;   // same-m0 blocks -> same XCD
        const int n0 = (t >> 3) * 128;
        gemm_core(Xbf, WqT, DM, m0, n0, As, Bs, acc);
        const float QS = 0.125f * 1.4426950408889634f;  // 1/sqrt(Hd) * log2(e)
#pragma unroll
        for (int i = 0; i < 4; i++) {
#pragma unroll
            for (int j = 0; j < 4; j++) {
                int n = n0 + wn + j * 16 + col;
                int mb = m0 + wm + i * 16 + quad * 4;
                float bv = bq[n];
#pragma unroll
                for (int ii = 0; ii < 4; ii++)
                    Qb[(mb + ii) * DM + n] = f2bh((acc[i][j][ii] + bv) * QS);
            }
        }
    } else {                                // ---- KV-proj: M=2048 (16 strips), N=2048 ----
        const int loc = bid - 512;
        const int xg = loc & 7, t = loc >> 3;
        const int m0 = (xg + 8 * (t & 1)) * 128;
        const int n0 = (t >> 1) * 128;
        gemm_core(Cbf, WkvT, DM, m0, n0, As, Bs, acc);
#pragma unroll
        for (int i = 0; i < 4; i++) {
#pragma unroll
            for (int j = 0; j < 4; j++) {
                int n = n0 + wn + j * 16 + col;
                int mb = m0 + wm + i * 16 + quad * 4;
                float bv = bkv[n];
                if (n < 1024) {
                    int h = n >> 6, d = n & 63;
#pragma unroll
                    for (int ii = 0; ii < 4; ii++) {
                        int m = mb + ii; int b = m >> 9, s = m & 511;
                        Kb[(((b * NH + h) * SS) + s) * HD + d] = f2bh(acc[i][j][ii] + bv);
                    }
                } else {
                    int q = n - 1024; int h = q >> 6, d = q & 63;
#pragma unroll
                    for (int ii = 0; ii < 4; ii++) {
                        int m = mb + ii; int b = m >> 9, s = m & 511;
                        Vtb[(((b * NH + h) * HD) + d) * SS + s] = f2bh(acc[i][j][ii] + bv);
                    }
                }
            }
        }
    }
}

// ---------------- out-proj: O@Wp + bp -> f32 ----------------
__global__ __launch_bounds__(256, 3)
void gemm_out(const unsigned short* __restrict__ Ob, const unsigned short* __restrict__ WpT,
              const float* __restrict__ bp, float* __restrict__ out) {
    __shared__ __align__(16) unsigned short As[128 * 64];
    __shared__ __align__(16) unsigned short Bs[128 * 64];
    const int tid = threadIdx.x;
    const int l = tid & 63;
    const int quad = l >> 4, col = l & 15;
    const int w = tid >> 6;
    const int wm = (w & 1) * 64, wn = (w >> 1) * 64;
    const int bid = blockIdx.x;
    const int xg = bid & 7, t = bid >> 3;
    const int m0 = (xg + 8 * (t & 7)) * 128;       // XCD-locality swizzle
    const int n0 = (t >> 3) * 128;

    const f32x4 zero = {0.f, 0.f, 0.f, 0.f};
    f32x4 acc[4][4];
#pragma unroll
    for (int i = 0; i < 4; i++)
#pragma unroll
        for (int j = 0; j < 4; j++) acc[i][j] = zero;

    gemm_core(Ob, WpT, DM, m0, n0, As, Bs, acc);

#pragma unroll
    for (int i = 0; i < 4; i++) {
#pragma unroll
        for (int j = 0; j < 4; j++) {
            int n = n0 + wn + j * 16 + col;
            int mb = m0 + wm + i * 16 + quad * 4;
            float bv = bp[n];
#pragma unroll
            for (int ii = 0; ii < 4; ii++)
                out[(mb + ii) * DM + n] = acc[i][j][ii] + bv;
        }
    }
}

// ---------------- flash attention: 256 thr, 4 waves x 32 q-rows, 32x32 MFMA -------
// Occupancy-oriented: 34KB LDS -> 4 blocks/CU; the two 32-s tiles of each 64-chunk
// are processed SEQUENTIALLY so only one f32x16 score acc is live (reg pressure).
// Swapped QK^T (lane owns one q-column), register P-build via permlane32_swap,
// raw v_exp_f32 for softmax exp.
// NOTE: each 64x64 tile is staged by TWO GLL sweeps of 2048 elements each
// (256 thr x 8 elem); second sweep offset is 2048, NOT 4096 (= next buffer!).
__global__ __launch_bounds__(256, 4)
void flash_attn(const unsigned short* __restrict__ Q, const unsigned short* __restrict__ Kb,
                const unsigned short* __restrict__ Vt, const float* __restrict__ mbias,
                unsigned short* __restrict__ O) {
    const int bid = blockIdx.x;
    const int xg = bid & 7, tq = bid >> 3;
    const int tb = tq & 15;                // T-tile (128 rows) within (b,h)
    const int bh = xg + 8 * (tq >> 4);     // same bh -> same XCD
    const int b = bh >> 4;
    const int tid = threadIdx.x;
    const int w = tid >> 6, l = tid & 63;
    const int lq = l & 31, hi = l >> 5;

    __shared__ __align__(16) unsigned short Ks[2][64 * 64];   // [s][d], piece-swizzled
    __shared__ __align__(16) unsigned short Vs[2][64 * 64];   // [d][s], piece-swizzled
    __shared__ float biasS[SS];

    const unsigned short* Kh = Kb + bh * SS * HD;
    const unsigned short* Vh = Vt + bh * HD * SS;

    float bv0 = mbias[b * SS + tid];
    float bv1 = mbias[b * SS + 256 + tid];
    biasS[tid] = bv0; biasS[tid + 256] = bv1;
    const int allon = __syncthreads_and((bv0 == 0.0f) && (bv1 == 0.0f));

    const int rowbase = b * TT + tb * 128 + w * 32;
    const int hd0 = (bh & 15) * HD;

    // Q fragments: B-operand, lane holds q = lq, k(d)-slice = 16*ch + 8*hi .. +8
    const unsigned short* qrow = Q + (size_t)(rowbase + lq) * DM + hd0;
    bf16x8 qf[4];
#pragma unroll
    for (int ch = 0; ch < 4; ++ch)
        qf[ch] = *(const bf16x8*)(qrow + ch * 16 + hi * 8);

    // staging (2 GLLs each for K and V; 256 threads cover rows 0..31 / 32..63)
    const int r0 = tid >> 3, sp = tid & 7;
    const int r1 = r0 + 32;
    const int kgo0 = r0 * HD + ((sp ^ (r0 & 7)) * 8);
    const int kgo1 = r1 * HD + ((sp ^ (r1 & 7)) * 8);
    const int vgo0 = r0 * SS + ((sp ^ (r0 & 7)) * 8);
    const int vgo1 = r1 * SS + ((sp ^ (r1 & 7)) * 8);

    GLL(Kh + kgo0, &Ks[0][tid * 8]);
    GLL(Kh + kgo1, &Ks[0][2048 + tid * 8]);
    GLL(Vh + vgo0, &Vs[0][tid * 8]);
    GLL(Vh + vgo1, &Vs[0][2048 + tid * 8]);

    const f32x16 zero16 = {0.f,0.f,0.f,0.f,0.f,0.f,0.f,0.f,
                           0.f,0.f,0.f,0.f,0.f,0.f,0.f,0.f};
    f32x16 oacc0 = zero16, oacc1 = zero16;   // d-tiles 0..31 / 32..63
    float lsum = 0.f;

    for (int it = 0; it < SS / 64; ++it) {
        const int s0 = it * 64;
        const int buf = it & 1;
        __syncthreads();
        if (it + 1 < SS / 64) {
            GLL(Kh + (s0 + 64) * HD + kgo0, &Ks[buf ^ 1][tid * 8]);
            GLL(Kh + (s0 + 64) * HD + kgo1, &Ks[buf ^ 1][2048 + tid * 8]);
            GLL(Vh + (s0 + 64) + vgo0, &Vs[buf ^ 1][tid * 8]);
            GLL(Vh + (s0 + 64) + vgo1, &Vs[buf ^ 1][2048 + tid * 8]);
        }

#pragma unroll
        for (int t = 0; t < 2; ++t) {
            const int rk = lq + 32 * t;             // K row for this 32-s tile
            // ---- QK^T ----
            f32x16 cs = zero16;
            __builtin_amdgcn_s_setprio(1);
#pragma unroll
            for (int ch = 0; ch < 4; ++ch) {
                bf16x8 kf = *(const bf16x8*)&Ks[buf][rk * 64 + (((2 * ch + hi) ^ (lq & 7)) * 8)];
                cs = MFMA32(kf, qf[ch], cs);
            }
            __builtin_amdgcn_s_setprio(0);

            // ---- softmax (lane-local) + in-register P-fragment build ----
            float pr[16];
#pragma unroll
            for (int r = 0; r < 16; ++r) {
                float sc = cs[r];
                if (!allon)
                    sc += biasS[s0 + 32 * t + ((r & 3) + 8 * (r >> 2) + 4 * hi)];
                pr[r] = fexp2(sc);
            }
            lsum += ((pr[0] + pr[1]) + (pr[2] + pr[3])) + ((pr[4] + pr[5]) + (pr[6] + pr[7]))
                  + ((pr[8] + pr[9]) + (pr[10] + pr[11])) + ((pr[12] + pr[13]) + (pr[14] + pr[15]));
            unsigned int wd0 = pk2(pr[0], pr[1]),   wd1 = pk2(pr[2], pr[3]);
            unsigned int wd2 = pk2(pr[4], pr[5]),   wd3 = pk2(pr[6], pr[7]);
            unsigned int wd4 = pk2(pr[8], pr[9]),   wd5 = pk2(pr[10], pr[11]);
            unsigned int wd6 = pk2(pr[12], pr[13]), wd7 = pk2(pr[14], pr[15]);
            pl32swap(wd0, wd2); pl32swap(wd1, wd3);
            pl32swap(wd4, wd6); pl32swap(wd5, wd7);
            union { unsigned int u[4]; bf16x8 v; } f0, f1;
            f0.u[0] = wd0; f0.u[1] = wd1; f0.u[2] = wd2; f0.u[3] = wd3;
            f1.u[0] = wd4; f1.u[1] = wd5; f1.u[2] = wd6; f1.u[3] = wd7;
            bf16x8 pfrag[2];
            pfrag[0] = f0.v;
            pfrag[1] = f1.v;

            // ---- PV: O[q][d] += P[q][s] * V[s][d]; 2 d-tiles x 2 s-windows ----
            __builtin_amdgcn_s_setprio(1);
#pragma unroll
            for (int win = 0; win < 2; ++win) {
                const int p = 4 * t + 2 * win + hi;
                bf16x8 v0 = *(const bf16x8*)&Vs[buf][lq * 64 + ((p ^ (lq & 7)) * 8)];
                bf16x8 v1 = *(const bf16x8*)&Vs[buf][(lq + 32) * 64 + ((p ^ (lq & 7)) * 8)];
                oacc0 = MFMA32(pfrag[win], v0, oacc0);
                oacc1 = MFMA32(pfrag[win], v1, oacc1);
            }
            __builtin_amdgcn_s_setprio(0);
        }
    }

    // ---- epilogue: lsum total per q, broadcast inverse, scaled bf16 store ----
    lsum += __shfl_xor(lsum, 32);
    float inv = 1.0f / lsum;               // lane lq (hi=0/1) holds inv for q == lq
    union { float f; int i; } cv; cv.f = inv;
#pragma unroll
    for (int r = 0; r < 16; ++r) {
        const int qloc = (r & 3) + 8 * (r >> 2) + 4 * hi;
        union { int i; float f; } rv;
        rv.i = __builtin_amdgcn_ds_bpermute(4 * qloc, cv.i);
        const float iq = rv.f;
        unsigned short* orow = O + (size_t)(rowbase + qloc) * DM + hd0 + lq;
        orow[0]  = f2bh(oacc0[r] * iq);
        orow[32] = f2bh(oacc1[r] * iq);
    }
}

// ---------------- launcher ----------------
extern "C" void kernel_launch(void* const* d_in, const int* in_sizes, int n_in,
                              void* d_out, int out_size, void* d_ws, size_t ws_size,
                              hipStream_t stream) {
    const float* x    = (const float*)d_in[0];
    const float* ctx  = (const float*)d_in[1];
    const void*  cmsk = d_in[2];
    const float* Wq   = (const float*)d_in[3];
    const float* bq   = (const float*)d_in[4];
    const float* Wkv  = (const float*)d_in[5];
    const float* bkv  = (const float*)d_in[6];
    const float* Wp   = (const float*)d_in[7];
    const float* bp   = (const float*)d_in[8];
    float* out = (float*)d_out;

    char* ws = (char*)d_ws;
    size_t off = 0;
    auto alloc = [&](size_t bytes) -> void* {
        void* p = ws + off;
        off += (bytes + 255) & ~(size_t)255;
        return p;
    };
    const size_t NX = (size_t)BB * TT * DM;   // 8388608
    const size_t NC = (size_t)BB * SS * DM;   // 2097152
    unsigned short* Xbf  = (unsigned short*)alloc(NX * 2);
    unsigned short* Cbf  = (unsigned short*)alloc(NC * 2);
    unsigned short* WqT  = (unsigned short*)alloc((size_t)DM * DM * 2);
    unsigned short* WkvT = (unsigned short*)alloc((size_t)DM * 2 * DM * 2);
    unsigned short* WpT  = (unsigned short*)alloc((size_t)DM * DM * 2);
    unsigned short* Qb   = (unsigned short*)alloc(NX * 2);
    unsigned short* Kbf  = (unsigned short*)alloc(NC * 2);
    unsigned short* Vtb  = (unsigned short*)alloc(NC * 2);
    unsigned short* Ob   = (unsigned short*)alloc(NX * 2);
    float* mbias         = (float*)alloc((size_t)BB * SS * 4);

    prep<<<14337, 256, 0, stream>>>((const float4*)x, (const float4*)ctx,
                                    (const unsigned int*)cmsk, Wq, Wkv, Wp,
                                    (ushort4*)Xbf, (ushort4*)Cbf,
                                    WqT, WkvT, WpT, mbias);

    // Q-proj + KV-proj fused in one launch (512 + 256 blocks, 128x128 tiles)
    gemm_qkv<<<768, 256, 0, stream>>>(Xbf, WqT, bq, Qb, Cbf, WkvT, bkv, Kbf, Vtb);

    // attention: 1024 blocks of 256 threads (4 waves x 32 q-rows)
    flash_attn<<<BB * NH * (TT / 128), 256, 0, stream>>>(Qb, Kbf, Vtb, mbias, Ob);

    // out = O@Wp + bp (fp32)
    gemm_out<<<512, 256, 0, stream>>>(Ob, WpT, bp, out);
}

// Round 7
// 190.221 us; speedup vs baseline: 1.0983x; 1.0258x over previous
//
#include <hip/hip_runtime.h>

// ---------------- types / helpers ----------------
typedef __bf16 bf16x8 __attribute__((ext_vector_type(8)));
typedef float  f32x4  __attribute__((ext_vector_type(4)));
typedef float  f32x16 __attribute__((ext_vector_type(16)));
typedef unsigned int u32x2 __attribute__((ext_vector_type(2)));

#define MFMA(a, b, c)   __builtin_amdgcn_mfma_f32_16x16x32_bf16((a), (b), (c), 0, 0, 0)
#define MFMA32(a, b, c) __builtin_amdgcn_mfma_f32_32x32x16_bf16((a), (b), (c), 0, 0, 0)

// async global->LDS, 16B per lane. LDS dest must be wave-uniform base + lane*16.
#define GLL(g, l) __builtin_amdgcn_global_load_lds(                                  \
    (const __attribute__((address_space(1))) void*)(g),                              \
    (__attribute__((address_space(3))) void*)(l), 16, 0, 0)

#define BB 4
#define TT 2048
#define SS 512
#define DM 1024
#define NH 16
#define HD 64

__device__ __forceinline__ unsigned short f2bh(float f) {  // native v_cvt (RTNE)
    __bf16 h = (__bf16)f;
    union { __bf16 h; unsigned short u; } v; v.h = h;
    return v.u;
}

__device__ __forceinline__ unsigned int pk2(float a, float b) {  // (lo,hi) bf16 pair
    return (unsigned int)f2bh(a) | ((unsigned int)f2bh(b) << 16);
}

// v_permlane32_swap_b32: new_a = {a.lanes[0:31], b.lanes[0:31]},
//                        new_b = {a.lanes[32:63], b.lanes[32:63]}
__device__ __forceinline__ void pl32swap(unsigned int& a, unsigned int& b) {
    u32x2 r = __builtin_amdgcn_permlane32_swap(a, b, false, false);
    a = r[0]; b = r[1];
}

__device__ __forceinline__ float fexp2(float x) {  // raw v_exp_f32 (2^x)
    float e;
    asm("v_exp_f32 %0, %1" : "=v"(e) : "v"(x));
    return e;
}

// ---------------- fused prep: casts + weight transposes + mask expand ------------
__device__ __forceinline__ void tcast_tile(const float* __restrict__ in,
                                           unsigned short* __restrict__ out,
                                           int K, int N, int n0, int k0,
                                           float (*tile)[33], int tid) {
    int tx = tid & 31, ty = tid >> 5;
#pragma unroll
    for (int r = 0; r < 32; r += 8)
        tile[ty + r][tx] = in[(k0 + ty + r) * N + n0 + tx];
    __syncthreads();
    // vectorized store: each thread writes 4 consecutive u16 (8 B)
    int r2 = tid >> 3, cg = (tid & 7) * 4;
    ushort4 o;
    o.x = f2bh(tile[cg + 0][r2]);
    o.y = f2bh(tile[cg + 1][r2]);
    o.z = f2bh(tile[cg + 2][r2]);
    o.w = f2bh(tile[cg + 3][r2]);
    *(ushort4*)&out[(n0 + r2) * K + k0 + cg] = o;
}

__global__ __launch_bounds__(256)
void prep(const float4* __restrict__ x, const float4* __restrict__ ctx,
          const unsigned int* __restrict__ mw,
          const float* __restrict__ Wq, const float* __restrict__ Wkv,
          const float* __restrict__ Wp,
          ushort4* __restrict__ Xbf, ushort4* __restrict__ Cbf,
          unsigned short* __restrict__ WqT, unsigned short* __restrict__ WkvT,
          unsigned short* __restrict__ WpT, float* __restrict__ mbias) {
    __shared__ float tile[32][33];
    __shared__ int flags[2];
    const int bid = blockIdx.x, tid = threadIdx.x;
    if (bid < 8192) {
        int i = bid * 256 + tid;
        float4 v = x[i];
        ushort4 o; o.x = f2bh(v.x); o.y = f2bh(v.y); o.z = f2bh(v.z); o.w = f2bh(v.w);
        Xbf[i] = o;
    } else if (bid < 10240) {
        int i = (bid - 8192) * 256 + tid;
        float4 v = ctx[i];
        ushort4 o; o.x = f2bh(v.x); o.y = f2bh(v.y); o.z = f2bh(v.z); o.w = f2bh(v.w);
        Cbf[i] = o;
    } else if (bid < 11264) {
        int loc = bid - 10240;
        tcast_tile(Wq, WqT, DM, DM, (loc & 31) * 32, (loc >> 5) * 32, tile, tid);
    } else if (bid < 13312) {
        int loc = bid - 11264;
        tcast_tile(Wkv, WkvT, DM, 2 * DM, (loc & 63) * 32, (loc >> 6) * 32, tile, tid);
    } else if (bid < 14336) {
        int loc = bid - 13312;
        tcast_tile(Wp, WpT, DM, DM, (loc & 31) * 32, (loc >> 5) * 32, tile, tid);
    } else {
        if (tid == 0) { flags[0] = 1; flags[1] = 1; }
        __syncthreads();
        int okI = 1, okF = 1;
        for (int i = tid; i < 512; i += 256) {
            unsigned int w = mw[i];
            if (w > 1u) okI = 0;
            if (w != 0u && w != 0x3f800000u) okF = 0;
        }
        if (!okI) atomicAnd(&flags[0], 0);
        if (!okF) atomicAnd(&flags[1], 0);
        __syncthreads();
        bool wordLayout = (flags[0] != 0) || (flags[1] != 0);
        const unsigned char* mb = (const unsigned char*)mw;
        for (int s = tid; s < BB * SS; s += 256) {
            bool on = wordLayout ? (mw[s] != 0u) : (mb[s] != 0);
            mbias[s] = on ? 0.0f : -1e38f;
        }
    }
}

// ---------------- GEMM core: 256 threads, tile 128x128, BK=64 (m97 structure) -----
__device__ __forceinline__ void gemm_core(
    const unsigned short* __restrict__ A, const unsigned short* __restrict__ Bt,
    int K, int m0, int n0, unsigned short* As, unsigned short* Bs,
    f32x4 (*acc)[4]) {
    const int tid = threadIdx.x;
    const int l = tid & 63;
    const int quad = l >> 4, col = l & 15;
    const int w = tid >> 6;
    const int wm = (w & 1) * 64, wn = (w >> 1) * 64;
    const int arow = tid >> 3;                       // 0..31
    const int apiece = (tid & 7) ^ (arow & 7);
    const unsigned short* Ab = A + (size_t)(m0 + arow) * K + apiece * 8;
    const unsigned short* Bb = Bt + (size_t)(n0 + arow) * K + apiece * 8;

    for (int k0 = 0; k0 < K; k0 += 64) {
        __syncthreads();
#pragma unroll
        for (int g = 0; g < 4; ++g)
            GLL(Ab + k0 + g * 32 * K, &As[g * 2048 + tid * 8]);
#pragma unroll
        for (int g = 0; g < 4; ++g)
            GLL(Bb + k0 + g * 32 * K, &Bs[g * 2048 + tid * 8]);
        __syncthreads();
#pragma unroll
        for (int k32 = 0; k32 < 2; ++k32) {
            bf16x8 af[4], bfr[4];
#pragma unroll
            for (int i = 0; i < 4; i++) {
                int rr = wm + i * 16 + col;
                af[i] = *(const bf16x8*)&As[rr * 64 + (((k32 * 4 + quad) ^ (rr & 7)) * 8)];
            }
#pragma unroll
            for (int j = 0; j < 4; j++) {
                int rr = wn + j * 16 + col;
                bfr[j] = *(const bf16x8*)&Bs[rr * 64 + (((k32 * 4 + quad) ^ (rr & 7)) * 8)];
            }
#pragma unroll
            for (int i = 0; i < 4; i++)
#pragma unroll
                for (int j = 0; j < 4; j++) acc[i][j] = MFMA(af[i], bfr[j], acc[i][j]);
        }
    }
}

// ---------------- fused Q-proj + KV-proj (one launch, 768 blocks) ----------------
// V-half blocks (n0>=1024) restage their 128x128 output tile through LDS (stride
// 130) so Vtb's [d][s] layout is written as contiguous 8B chunks instead of 2B
// scatters at 1KB stride (16 cache lines touched per store inst otherwise).
__global__ __launch_bounds__(256, 3)
void gemm_qkv(const unsigned short* __restrict__ Xbf, const unsigned short* __restrict__ WqT,
              const float* __restrict__ bq, unsigned short* __restrict__ Qb,
              const unsigned short* __restrict__ Cbf, const unsigned short* __restrict__ WkvT,
              const float* __restrict__ bkv, unsigned short* __restrict__ Kb,
              unsigned short* __restrict__ Vtb) {
    __shared__ __align__(16) unsigned short S[16640];   // As[8192]|Bs[8192]; reused as Tt[128][130]
    unsigned short* As = S;
    unsigned short* Bs = S + 8192;
    const int tid = threadIdx.x;
    const int l = tid & 63;
    const int quad = l >> 4, col = l & 15;
    const int w = tid >> 6;
    const int wm = (w & 1) * 64, wn = (w >> 1) * 64;
    const int bid = blockIdx.x;

    const f32x4 zero = {0.f, 0.f, 0.f, 0.f};
    f32x4 acc[4][4];
#pragma unroll
    for (int i = 0; i < 4; i++)
#pragma unroll
        for (int j = 0; j < 4; j++) acc[i][j] = zero;

    if (bid < 512) {                        // ---- Q-proj: M=8192 (64 strips), N=1024 ----
        const int xg = bid & 7, t = bid >> 3;
        const int m0 = (xg + 8 * (t & 7)) * 128;   // same-m0 blocks -> same XCD
        const int n0 = (t >> 3) * 128;
        gemm_core(Xbf, WqT, DM, m0, n0, As, Bs, acc);
        const float QS = 0.125f * 1.4426950408889634f;  // 1/sqrt(Hd) * log2(e)
#pragma unroll
        for (int i = 0; i < 4; i++) {
#pragma unroll
            for (int j = 0; j < 4; j++) {
                int n = n0 + wn + j * 16 + col;
                int mb = m0 + wm + i * 16 + quad * 4;
                float bv = bq[n];
#pragma unroll
                for (int ii = 0; ii < 4; ii++)
                    Qb[(mb + ii) * DM + n] = f2bh((acc[i][j][ii] + bv) * QS);
            }
        }
    } else {                                // ---- KV-proj: M=2048 (16 strips), N=2048 ----
        const int loc = bid - 512;
        const int xg = loc & 7, t = loc >> 3;
        const int m0 = (xg + 8 * (t & 1)) * 128;
        const int n0 = (t >> 1) * 128;
        gemm_core(Cbf, WkvT, DM, m0, n0, As, Bs, acc);
        if (n0 < 1024) {                    // ---- K-half: direct (coalesced) stores ----
#pragma unroll
            for (int i = 0; i < 4; i++) {
#pragma unroll
                for (int j = 0; j < 4; j++) {
                    int n = n0 + wn + j * 16 + col;
                    int mb = m0 + wm + i * 16 + quad * 4;
                    float bv = bkv[n];
                    int h = n >> 6, d = n & 63;
#pragma unroll
                    for (int ii = 0; ii < 4; ii++) {
                        int m = mb + ii; int b = m >> 9, s = m & 511;
                        Kb[(((b * NH + h) * SS) + s) * HD + d] = f2bh(acc[ii == ii ? i : i][j][ii] + bv);
                    }
                }
            }
        } else {                            // ---- V-half: LDS transpose restage ----
            __syncthreads();                // all waves done reading As/Bs
#pragma unroll
            for (int i = 0; i < 4; i++) {
#pragma unroll
                for (int j = 0; j < 4; j++) {
                    int nl = wn + j * 16 + col;
                    int ml = wm + i * 16 + quad * 4;
                    float bv = bkv[n0 + nl];
#pragma unroll
                    for (int ii = 0; ii < 4; ii++)
                        S[(ml + ii) * 130 + nl] = f2bh(acc[i][j][ii] + bv);
                }
            }
            __syncthreads();
            // thread -> one (h,d) row, 64 s-values, written as 8B contiguous chunks
            const int nl = tid >> 1, sc = (tid & 1) * 64;
            const int q = n0 - 1024 + nl;
            const int h = q >> 6, d = q & 63;
            const int b = m0 >> 9;
            unsigned short* vrow = Vtb + (((size_t)(b * NH + h) * HD) + d) * SS
                                       + (m0 & 511) + sc;
#pragma unroll
            for (int k = 0; k < 64; k += 4) {
                ushort4 o;
                o.x = S[(sc + k + 0) * 130 + nl];
                o.y = S[(sc + k + 1) * 130 + nl];
                o.z = S[(sc + k + 2) * 130 + nl];
                o.w = S[(sc + k + 3) * 130 + nl];
                *(ushort4*)&vrow[k] = o;
            }
        }
    }
}

// ---------------- out-proj: O@Wp + bp -> f32 ----------------
__global__ __launch_bounds__(256, 3)
void gemm_out(const unsigned short* __restrict__ Ob, const unsigned short* __restrict__ WpT,
              const float* __restrict__ bp, float* __restrict__ out) {
    __shared__ __align__(16) unsigned short As[128 * 64];
    __shared__ __align__(16) unsigned short Bs[128 * 64];
    const int tid = threadIdx.x;
    const int l = tid & 63;
    const int quad = l >> 4, col = l & 15;
    const int w = tid >> 6;
    const int wm = (w & 1) * 64, wn = (w >> 1) * 64;
    const int bid = blockIdx.x;
    const int xg = bid & 7, t = bid >> 3;
    const int m0 = (xg + 8 * (t & 7)) * 128;       // XCD-locality swizzle
    const int n0 = (t >> 3) * 128;

    const f32x4 zero = {0.f, 0.f, 0.f, 0.f};
    f32x4 acc[4][4];
#pragma unroll
    for (int i = 0; i < 4; i++)
#pragma unroll
        for (int j = 0; j < 4; j++) acc[i][j] = zero;

    gemm_core(Ob, WpT, DM, m0, n0, As, Bs, acc);

#pragma unroll
    for (int i = 0; i < 4; i++) {
#pragma unroll
        for (int j = 0; j < 4; j++) {
            int n = n0 + wn + j * 16 + col;
            int mb = m0 + wm + i * 16 + quad * 4;
            float bv = bp[n];
#pragma unroll
            for (int ii = 0; ii < 4; ii++)
                out[(mb + ii) * DM + n] = acc[i][j][ii] + bv;
        }
    }
}

// ---------------- flash attention: 256 thr, 4 waves x 32 q-rows, 32x32 MFMA -------
// Occupancy-oriented: 34KB LDS -> 4 blocks/CU; the two 32-s tiles of each 64-chunk
// are processed SEQUENTIALLY so only one f32x16 score acc is live (reg pressure).
// Swapped QK^T (lane owns one q-column), register P-build via permlane32_swap,
// raw v_exp_f32 for softmax exp.
// NOTE: each 64x64 tile is staged by TWO GLL sweeps of 2048 elements each
// (256 thr x 8 elem); second sweep offset is 2048, NOT 4096 (= next buffer!).
__global__ __launch_bounds__(256, 4)
void flash_attn(const unsigned short* __restrict__ Q, const unsigned short* __restrict__ Kb,
                const unsigned short* __restrict__ Vt, const float* __restrict__ mbias,
                unsigned short* __restrict__ O) {
    const int bid = blockIdx.x;
    const int xg = bid & 7, tq = bid >> 3;
    const int tb = tq & 15;                // T-tile (128 rows) within (b,h)
    const int bh = xg + 8 * (tq >> 4);     // same bh -> same XCD
    const int b = bh >> 4;
    const int tid = threadIdx.x;
    const int w = tid >> 6, l = tid & 63;
    const int lq = l & 31, hi = l >> 5;

    __shared__ __align__(16) unsigned short Ks[2][64 * 64];   // [s][d], piece-swizzled
    __shared__ __align__(16) unsigned short Vs[2][64 * 64];   // [d][s], piece-swizzled
    __shared__ float biasS[SS];

    const unsigned short* Kh = Kb + bh * SS * HD;
    const unsigned short* Vh = Vt + bh * HD * SS;

    float bv0 = mbias[b * SS + tid];
    float bv1 = mbias[b * SS + 256 + tid];
    biasS[tid] = bv0; biasS[tid + 256] = bv1;
    const int allon = __syncthreads_and((bv0 == 0.0f) && (bv1 == 0.0f));

    const int rowbase = b * TT + tb * 128 + w * 32;
    const int hd0 = (bh & 15) * HD;

    // Q fragments: B-operand, lane holds q = lq, k(d)-slice = 16*ch + 8*hi .. +8
    const unsigned short* qrow = Q + (size_t)(rowbase + lq) * DM + hd0;
    bf16x8 qf[4];
#pragma unroll
    for (int ch = 0; ch < 4; ++ch)
        qf[ch] = *(const bf16x8*)(qrow + ch * 16 + hi * 8);

    // staging (2 GLLs each for K and V; 256 threads cover rows 0..31 / 32..63)
    const int r0 = tid >> 3, sp = tid & 7;
    const int r1 = r0 + 32;
    const int kgo0 = r0 * HD + ((sp ^ (r0 & 7)) * 8);
    const int kgo1 = r1 * HD + ((sp ^ (r1 & 7)) * 8);
    const int vgo0 = r0 * SS + ((sp ^ (r0 & 7)) * 8);
    const int vgo1 = r1 * SS + ((sp ^ (r1 & 7)) * 8);

    GLL(Kh + kgo0, &Ks[0][tid * 8]);
    GLL(Kh + kgo1, &Ks[0][2048 + tid * 8]);
    GLL(Vh + vgo0, &Vs[0][tid * 8]);
    GLL(Vh + vgo1, &Vs[0][2048 + tid * 8]);

    const f32x16 zero16 = {0.f,0.f,0.f,0.f,0.f,0.f,0.f,0.f,
                           0.f,0.f,0.f,0.f,0.f,0.f,0.f,0.f};
    f32x16 oacc0 = zero16, oacc1 = zero16;   // d-tiles 0..31 / 32..63
    float lsum = 0.f;

    for (int it = 0; it < SS / 64; ++it) {
        const int s0 = it * 64;
        const int buf = it & 1;
        __syncthreads();
        if (it + 1 < SS / 64) {
            GLL(Kh + (s0 + 64) * HD + kgo0, &Ks[buf ^ 1][tid * 8]);
            GLL(Kh + (s0 + 64) * HD + kgo1, &Ks[buf ^ 1][2048 + tid * 8]);
            GLL(Vh + (s0 + 64) + vgo0, &Vs[buf ^ 1][tid * 8]);
            GLL(Vh + (s0 + 64) + vgo1, &Vs[buf ^ 1][2048 + tid * 8]);
        }

#pragma unroll
        for (int t = 0; t < 2; ++t) {
            const int rk = lq + 32 * t;             // K row for this 32-s tile
            // ---- QK^T ----
            f32x16 cs = zero16;
            __builtin_amdgcn_s_setprio(1);
#pragma unroll
            for (int ch = 0; ch < 4; ++ch) {
                bf16x8 kf = *(const bf16x8*)&Ks[buf][rk * 64 + (((2 * ch + hi) ^ (lq & 7)) * 8)];
                cs = MFMA32(kf, qf[ch], cs);
            }
            __builtin_amdgcn_s_setprio(0);

            // ---- softmax (lane-local) + in-register P-fragment build ----
            float pr[16];
#pragma unroll
            for (int r = 0; r < 16; ++r) {
                float sc = cs[r];
                if (!allon)
                    sc += biasS[s0 + 32 * t + ((r & 3) + 8 * (r >> 2) + 4 * hi)];
                pr[r] = fexp2(sc);
            }
            lsum += ((pr[0] + pr[1]) + (pr[2] + pr[3])) + ((pr[4] + pr[5]) + (pr[6] + pr[7]))
                  + ((pr[8] + pr[9]) + (pr[10] + pr[11])) + ((pr[12] + pr[13]) + (pr[14] + pr[15]));
            unsigned int wd0 = pk2(pr[0], pr[1]),   wd1 = pk2(pr[2], pr[3]);
            unsigned int wd2 = pk2(pr[4], pr[5]),   wd3 = pk2(pr[6], pr[7]);
            unsigned int wd4 = pk2(pr[8], pr[9]),   wd5 = pk2(pr[10], pr[11]);
            unsigned int wd6 = pk2(pr[12], pr[13]), wd7 = pk2(pr[14], pr[15]);
            pl32swap(wd0, wd2); pl32swap(wd1, wd3);
            pl32swap(wd4, wd6); pl32swap(wd5, wd7);
            union { unsigned int u[4]; bf16x8 v; } f0, f1;
            f0.u[0] = wd0; f0.u[1] = wd1; f0.u[2] = wd2; f0.u[3] = wd3;
            f1.u[0] = wd4; f1.u[1] = wd5; f1.u[2] = wd6; f1.u[3] = wd7;
            bf16x8 pfrag[2];
            pfrag[0] = f0.v;
            pfrag[1] = f1.v;

            // ---- PV: O[q][d] += P[q][s] * V[s][d]; 2 d-tiles x 2 s-windows ----
            __builtin_amdgcn_s_setprio(1);
#pragma unroll
            for (int win = 0; win < 2; ++win) {
                const int p = 4 * t + 2 * win + hi;
                bf16x8 v0 = *(const bf16x8*)&Vs[buf][lq * 64 + ((p ^ (lq & 7)) * 8)];
                bf16x8 v1 = *(const bf16x8*)&Vs[buf][(lq + 32) * 64 + ((p ^ (lq & 7)) * 8)];
                oacc0 = MFMA32(pfrag[win], v0, oacc0);
                oacc1 = MFMA32(pfrag[win], v1, oacc1);
            }
            __builtin_amdgcn_s_setprio(0);
        }
    }

    // ---- epilogue: lsum total per q, broadcast inverse, scaled bf16 store ----
    lsum += __shfl_xor(lsum, 32);
    float inv = 1.0f / lsum;               // lane lq (hi=0/1) holds inv for q == lq
    union { float f; int i; } cv; cv.f = inv;
#pragma unroll
    for (int r = 0; r < 16; ++r) {
        const int qloc = (r & 3) + 8 * (r >> 2) + 4 * hi;
        union { int i; float f; } rv;
        rv.i = __builtin_amdgcn_ds_bpermute(4 * qloc, cv.i);
        const float iq = rv.f;
        unsigned short* orow = O + (size_t)(rowbase + qloc) * DM + hd0 + lq;
        orow[0]  = f2bh(oacc0[r] * iq);
        orow[32] = f2bh(oacc1[r] * iq);
    }
}

// ---------------- launcher ----------------
extern "C" void kernel_launch(void* const* d_in, const int* in_sizes, int n_in,
                              void* d_out, int out_size, void* d_ws, size_t ws_size,
                              hipStream_t stream) {
    const float* x    = (const float*)d_in[0];
    const float* ctx  = (const float*)d_in[1];
    const void*  cmsk = d_in[2];
    const float* Wq   = (const float*)d_in[3];
    const float* bq   = (const float*)d_in[4];
    const float* Wkv  = (const float*)d_in[5];
    const float* bkv  = (const float*)d_in[6];
    const float* Wp   = (const float*)d_in[7];
    const float* bp   = (const float*)d_in[8];
    float* out = (float*)d_out;

    char* ws = (char*)d_ws;
    size_t off = 0;
    auto alloc = [&](size_t bytes) -> void* {
        void* p = ws + off;
        off += (bytes + 255) & ~(size_t)255;
        return p;
    };
    const size_t NX = (size_t)BB * TT * DM;   // 8388608
    const size_t NC = (size_t)BB * SS * DM;   // 2097152
    unsigned short* Xbf  = (unsigned short*)alloc(NX * 2);
    unsigned short* Cbf  = (unsigned short*)alloc(NC * 2);
    unsigned short* WqT  = (unsigned short*)alloc((size_t)DM * DM * 2);
    unsigned short* WkvT = (unsigned short*)alloc((size_t)DM * 2 * DM * 2);
    unsigned short* WpT  = (unsigned short*)alloc((size_t)DM * DM * 2);
    unsigned short* Qb   = (unsigned short*)alloc(NX * 2);
    unsigned short* Kbf  = (unsigned short*)alloc(NC * 2);
    unsigned short* Vtb  = (unsigned short*)alloc(NC * 2);
    unsigned short* Ob   = (unsigned short*)alloc(NX * 2);
    float* mbias         = (float*)alloc((size_t)BB * SS * 4);

    prep<<<14337, 256, 0, stream>>>((const float4*)x, (const float4*)ctx,
                                    (const unsigned int*)cmsk, Wq, Wkv, Wp,
                                    (ushort4*)Xbf, (ushort4*)Cbf,
                                    WqT, WkvT, WpT, mbias);

    // Q-proj + KV-proj fused in one launch (512 + 256 blocks, 128x128 tiles)
    gemm_qkv<<<768, 256, 0, stream>>>(Xbf, WqT, bq, Qb, Cbf, WkvT, bkv, Kbf, Vtb);

    // attention: 1024 blocks of 256 threads (4 waves x 32 q-rows)
    flash_attn<<<BB * NH * (TT / 128), 256, 0, stream>>>(Qb, Kbf, Vtb, mbias, Ob);

    // out = O@Wp + bp (fp32)
    gemm_out<<<512, 256, 0, stream>>>(Ob, WpT, bp, out);
}